// Round 8
// baseline (217.710 us; speedup 1.0000x reference)
//
#include <hip/hip_runtime.h>
#include <math.h>

typedef unsigned short u16;
typedef unsigned int u32;
typedef __attribute__((ext_vector_type(8))) short short8;
typedef __attribute__((ext_vector_type(4))) float f32x4;

__device__ __forceinline__ u16 f2bf(float f) {
    u32 u = __float_as_uint(f);
    u = (u + 0x7FFFu + ((u >> 16) & 1u)) >> 16;   // RNE
    return (u16)u;
}
__device__ __forceinline__ float bf2f(u16 h) {
    return __uint_as_float(((u32)h) << 16);
}

// ============ conversion kernels ============

// fp32 -> bf16: text, html, edgeemb(64x384), posemb(13x384)
__global__ __launch_bounds__(256)
void cvt4(const float4* __restrict__ a, int na4,
          const float4* __restrict__ b, int nb4,
          const float4* __restrict__ c, int nc4,
          const float4* __restrict__ d, int nd4,
          u16* __restrict__ oa, u16* __restrict__ ob,
          u16* __restrict__ oc, u16* __restrict__ od)
{
    int idx = blockIdx.x * 256 + threadIdx.x;
    const int tot = na4 + nb4 + nc4 + nd4;
    for (; idx < tot; idx += gridDim.x * 256) {
        float4 v; u16* o;
        int t = idx;
        if (t < na4)      { v = a[t]; o = oa + (long)t * 4; }
        else if ((t -= na4) < nb4) { v = b[t]; o = ob + (long)t * 4; }
        else if ((t -= nb4) < nc4) { v = c[t]; o = oc + (long)t * 4; }
        else { t -= nc4;    v = d[t]; o = od + (long)t * 4; }
        u32 lo = (u32)f2bf(v.x) | ((u32)f2bf(v.y) << 16);
        u32 hi = (u32)f2bf(v.z) | ((u32)f2bf(v.w) << 16);
        uint2 pk; pk.x = lo; pk.y = hi;
        *reinterpret_cast<uint2*>(o) = pk;
    }
}

struct WP { const float* p[10]; };
struct WD { u16* d[10]; };

// W [384][384] fp32 -> W^T bf16 at per-weight destination
__global__ __launch_bounds__(1024)
void wtrans(WP w, WD wd)
{
    __shared__ float t[32][33];
    const int z = blockIdx.z;
    const float* W = w.p[z];
    const int k = blockIdx.x * 32 + threadIdx.y;   // row of W
    const int n = blockIdx.y * 32 + threadIdx.x;   // col of W
    t[threadIdx.y][threadIdx.x] = W[k * 384 + n];
    __syncthreads();
    const int no = blockIdx.y * 32 + threadIdx.y;
    const int ko = blockIdx.x * 32 + threadIdx.x;
    wd.d[z][no * 384 + ko] = f2bf(t[threadIdx.x][threadIdx.y]);
}

// ============ 128x128 MFMA NT core (r4-verified m97 structure) ============
// 128x128 C-tile of A[128 rows, lda] . B[128 rows, ldb]^T over K (K%32==0).
// Single-buffered [128][32] bf16 LDS per matrix, global_load_lds width 16,
// 4 waves (2x2 of 64x64), 16 MFMA per K-step.
__device__ __forceinline__ void mfma_core128(
    const u16* __restrict__ A, int lda,
    const u16* __restrict__ B, int ldb, int K,
    u16* __restrict__ As, u16* __restrict__ Bs,
    f32x4 (&acc)[4][4])
{
    const int tid  = threadIdx.x;
    const int wid  = tid >> 6;
    const int lane = tid & 63;
    const int wr = wid >> 1, wc = wid & 1;
    const int lane15 = lane & 15;
    const int kg = (lane >> 4) * 8;          // k offset of this lane's fragment
    const int srow = lane >> 2;              // staging row within 16-row group
    const int scol = (lane & 3) * 8;         // staging col (8 bf16 = 16B)

    #pragma unroll
    for (int i = 0; i < 4; ++i)
        #pragma unroll
        for (int j = 0; j < 4; ++j)
            acc[i][j] = (f32x4){0.f, 0.f, 0.f, 0.f};

    for (int k0 = 0; k0 < K; k0 += 32) {
        #pragma unroll
        for (int i = 0; i < 2; ++i) {
            const int rg = (wid * 2 + i) * 16;
            const u16* ga = A + (long)(rg + srow) * lda + (k0 + scol);
            const u16* gb = B + (long)(rg + srow) * ldb + (k0 + scol);
            u16* la = As + (wid * 2 + i) * 512;   // wave-uniform base
            u16* lb = Bs + (wid * 2 + i) * 512;
            __builtin_amdgcn_global_load_lds(
                (const __attribute__((address_space(1))) void*)ga,
                (__attribute__((address_space(3))) void*)la, 16, 0, 0);
            __builtin_amdgcn_global_load_lds(
                (const __attribute__((address_space(1))) void*)gb,
                (__attribute__((address_space(3))) void*)lb, 16, 0, 0);
        }
        __syncthreads();   // drains vmcnt -> tiles visible

        short8 af[4], bf[4];
        #pragma unroll
        for (int mi = 0; mi < 4; ++mi)
            af[mi] = *reinterpret_cast<const short8*>(
                As + (wr * 64 + mi * 16 + lane15) * 32 + kg);
        #pragma unroll
        for (int ni = 0; ni < 4; ++ni)
            bf[ni] = *reinterpret_cast<const short8*>(
                Bs + (wc * 64 + ni * 16 + lane15) * 32 + kg);
        #pragma unroll
        for (int mi = 0; mi < 4; ++mi)
            #pragma unroll
            for (int ni = 0; ni < 4; ++ni)
                acc[mi][ni] = __builtin_amdgcn_mfma_f32_16x16x32_bf16(
                    af[mi], bf[ni], acc[mi][ni], 0, 0, 0);
        __syncthreads();   // LDS reuse next iteration
    }
}

// ===== grouped f32-output GEMM (scores+bias: plain store / PV: split-K atomic) =====
struct Seg {
    const u16* A; const u16* B; float* C;
    long sA, sB, sC;
    int lda, ldb, ldc, K, nbx, nbxSh, start, kOff;
};
struct Segs { Seg s[8]; };

template<int NSEG, bool ATOMIC>
__global__ __launch_bounds__(256)
void gemm_grouped(Segs d)
{
    __shared__ __align__(16) u16 As[4096];
    __shared__ __align__(16) u16 Bs[4096];
    const int bid = blockIdx.x;
    Seg sg = d.s[0];                         // static-index selects only
    if (NSEG > 1 && bid >= d.s[1].start) sg = d.s[1];
    if (NSEG > 2 && bid >= d.s[2].start) sg = d.s[2];
    if (NSEG > 3 && bid >= d.s[3].start) sg = d.s[3];
    if (NSEG > 4 && bid >= d.s[4].start) sg = d.s[4];
    if (NSEG > 5 && bid >= d.s[5].start) sg = d.s[5];
    if (NSEG > 6 && bid >= d.s[6].start) sg = d.s[6];
    if (NSEG > 7 && bid >= d.s[7].start) sg = d.s[7];

    const int local = bid - sg.start;
    const int bx = local & (sg.nbx - 1);
    const int by = local >> sg.nbxSh;
    const int z  = blockIdx.y;
    const int m0 = bx * 128, n0 = by * 128;

    const u16* A = sg.A + (long)z * sg.sA + (long)m0 * sg.lda + sg.kOff;
    const u16* B = sg.B + (long)z * sg.sB + (long)n0 * sg.ldb + sg.kOff;

    f32x4 acc[4][4];
    mfma_core128(A, sg.lda, B, sg.ldb, sg.K, As, Bs, acc);

    const int tid = threadIdx.x;
    const int wid = tid >> 6, lane = tid & 63;
    const int wr = wid >> 1, wc = wid & 1;
    const int lane15 = lane & 15;
    const int r0 = (lane >> 4) * 4;

    // C/D frag: col = lane&15, row = (lane>>4)*4 + reg  [m89]
    float* C = sg.C + (long)z * sg.sC;
    #pragma unroll
    for (int mi = 0; mi < 4; ++mi)
        #pragma unroll
        for (int r = 0; r < 4; ++r) {
            const int row = m0 + wr * 64 + mi * 16 + r0 + r;
            float* crow = C + (long)row * sg.ldc + n0 + wc * 64 + lane15;
            #pragma unroll
            for (int ni = 0; ni < 4; ++ni) {
                if (ATOMIC)
                    __hip_atomic_fetch_add(crow + ni * 16, acc[mi][ni][r],
                                           __ATOMIC_RELAXED,
                                           __HIP_MEMORY_SCOPE_AGENT);
                else
                    crow[ni * 16] = acc[mi][ni][r];
            }
        }
}

// ============ grouped projection GEMM (V^T + packed QK epilogue) ============
struct PSeg {
    const u16* A; const u16* Bw; u16* QK; u16* VT;
    int lvtSh, vtOff, nbx, nbxSh, start, pad;
};
struct PSegs { PSeg s[2]; };

__global__ __launch_bounds__(256)
void proj_grouped(PSegs d)
{
    __shared__ __align__(16) u16 As[4096];
    __shared__ __align__(16) u16 Bs[4096];
    const int bid = blockIdx.x;
    PSeg sg = d.s[0];
    if (bid >= d.s[1].start) sg = d.s[1];

    const int local = bid - sg.start;
    const int bx = local & (sg.nbx - 1);
    const int by = local >> sg.nbxSh;
    const int m0 = bx * 128, n0 = by * 128;

    const u16* A = sg.A + (long)m0 * 384;
    const u16* B = sg.Bw + (long)n0 * 384;

    f32x4 acc[4][4];
    mfma_core128(A, 384, B, 384, 384, As, Bs, acc);

    const int tid = threadIdx.x;
    const int wid = tid >> 6, lane = tid & 63;
    const int wr = wid >> 1, wc = wid & 1;
    const int lane15 = lane & 15;
    const int r0 = (lane >> 4) * 4;
    const int lmask = (1 << sg.lvtSh) - 1;

    if (n0 < 384) {
        // V columns -> stacked transposed bf16: VT[(bz*384+col)*1536 + vtOff + l]
        #pragma unroll
        for (int mi = 0; mi < 4; ++mi) {
            const int row = m0 + wr * 64 + mi * 16 + r0;
            const int bz = row >> sg.lvtSh;
            const int l  = row & lmask;
            #pragma unroll
            for (int ni = 0; ni < 4; ++ni) {
                const int col = n0 + wc * 64 + ni * 16 + lane15;
                u32 lo = (u32)f2bf(acc[mi][ni][0]) | ((u32)f2bf(acc[mi][ni][1]) << 16);
                u32 hi = (u32)f2bf(acc[mi][ni][2]) | ((u32)f2bf(acc[mi][ni][3]) << 16);
                uint2 pk; pk.x = lo; pk.y = hi;
                *reinterpret_cast<uint2*>(
                    sg.VT + ((long)bz * 384 + col) * 1536 + sg.vtOff + l) = pk;
            }
        }
    } else {
        // Q/K columns -> packed bf16 [row][1536]
        #pragma unroll
        for (int mi = 0; mi < 4; ++mi)
            #pragma unroll
            for (int r = 0; r < 4; ++r) {
                const int row = m0 + wr * 64 + mi * 16 + r0 + r;
                u16* qrow = sg.QK + (long)row * 1536 + (n0 - 384) + wc * 64 + lane15;
                #pragma unroll
                for (int ni = 0; ni < 4; ++ni)
                    qrow[ni * 16] = f2bf(acc[mi][ni][r]);
            }
    }
}

// ============ fused softmax: one block per output row, two segments ============

__device__ __forceinline__ float blockReduceMax(float v, float* red, int tid) {
    #pragma unroll
    for (int o = 32; o >= 1; o >>= 1) v = fmaxf(v, __shfl_xor(v, o));
    if ((tid & 63) == 0) red[tid >> 6] = v;
    __syncthreads();
    return fmaxf(fmaxf(red[0], red[1]), fmaxf(red[2], red[3]));
}
__device__ __forceinline__ float blockReduceSum(float v, float* red, int tid) {
    #pragma unroll
    for (int o = 32; o >= 1; o >>= 1) v += __shfl_xor(v, o);
    if ((tid & 63) == 0) red[4 + (tid >> 6)] = v;
    __syncthreads();
    return red[4] + red[5] + red[6] + red[7];
}

// blocks 0..2047: html rows (h2h cols 0-511, h2t cols 512-1535)
// blocks 2048..6143: text rows (t2h cols 0-511, t2t cols 512-1535)
__global__ __launch_bounds__(256)
void softmax_fused(const float* __restrict__ scoresH, u16* __restrict__ probsH,
                   const float* __restrict__ scoresT, u16* __restrict__ probsT,
                   const float* __restrict__ qe, const float* __restrict__ qp,
                   const int* __restrict__ H2Hmask,
                   const float* __restrict__ H2Tmask,
                   const float* __restrict__ T2Tmask, float scale)
{
    const int bid = blockIdx.x;
    const int tid = threadIdx.x;
    __shared__ float qsh[64];
    __shared__ float red[8];

    if (bid < 2048) {
        const int b = bid >> 9, i = bid & 511;
        const long rbase = ((long)b * 512 + i) * 1536;
        const float* rowS = scoresH + rbase;
        u16* rowP = probsH + rbase;
        const int*   mrow  = H2Hmask + ((long)b * 512 + i) * 512;
        const float* m2row = H2Tmask + ((long)b * 512 + i) * 1024;
        if (tid < 64) qsh[tid] = qe[((long)b * 512 + i) * 128 + tid];
        __syncthreads();

        // --- h2h (512) ---
        float x[2]; float mx = -1e30f;
        #pragma unroll
        for (int t = 0; t < 2; ++t) {
            const int j = tid + t * 256;
            const int m = mrow[j];
            float v = (rowS[j] + qsh[m]) * scale - 10000.f * (m == 0 ? 1.f : 0.f);
            x[t] = v; mx = fmaxf(mx, v);
        }
        mx = blockReduceMax(mx, red, tid);
        float s = 0.f;
        #pragma unroll
        for (int t = 0; t < 2; ++t) { x[t] = __expf(x[t] - mx); s += x[t]; }
        s = blockReduceSum(s, red, tid);
        float inv = 1.f / s;
        #pragma unroll
        for (int t = 0; t < 2; ++t) rowP[tid + t * 256] = f2bf(x[t] * inv);

        // --- h2t (1024, cols 512..1535) ---
        float y[4]; mx = -1e30f;
        #pragma unroll
        for (int t = 0; t < 4; ++t) {
            const int jj = tid + t * 256;
            float v = rowS[512 + jj] * scale - 10000.f * m2row[jj];
            y[t] = v; mx = fmaxf(mx, v);
        }
        mx = blockReduceMax(mx, red, tid);
        s = 0.f;
        #pragma unroll
        for (int t = 0; t < 4; ++t) { y[t] = __expf(y[t] - mx); s += y[t]; }
        s = blockReduceSum(s, red, tid);
        inv = 1.f / s;
        #pragma unroll
        for (int t = 0; t < 4; ++t) rowP[512 + tid + t * 256] = f2bf(y[t] * inv);
    } else {
        const int bid2 = bid - 2048;
        const int b = bid2 >> 10, i = bid2 & 1023;
        const long rbase = ((long)b * 1024 + i) * 1536;
        const float* rowS = scoresT + rbase;
        u16* rowP = probsT + rbase;
        const float* m2row = T2Tmask + ((long)b * 1024 + i) * 1024;
        if (tid < 13) qsh[tid] = qp[((long)b * 1024 + i) * 128 + tid];
        __syncthreads();

        // --- t2h (512, no mask) ---
        float x[2]; float mx = -1e30f;
        #pragma unroll
        for (int t = 0; t < 2; ++t) {
            const int j = tid + t * 256;
            float v = rowS[j] * scale;
            x[t] = v; mx = fmaxf(mx, v);
        }
        mx = blockReduceMax(mx, red, tid);
        float s = 0.f;
        #pragma unroll
        for (int t = 0; t < 2; ++t) { x[t] = __expf(x[t] - mx); s += x[t]; }
        s = blockReduceSum(s, red, tid);
        float inv = 1.f / s;
        #pragma unroll
        for (int t = 0; t < 2; ++t) rowP[tid + t * 256] = f2bf(x[t] * inv);

        // --- t2t (1024, cols 512..1535) ---
        float y[4]; mx = -1e30f;
        #pragma unroll
        for (int t = 0; t < 4; ++t) {
            const int jj = tid + t * 256;
            int pos = jj - i;
            pos = (pos < -6 ? -6 : (pos > 6 ? 6 : pos)) + 6;
            float v = (rowS[512 + jj] + qsh[pos]) * scale - 10000.f * m2row[jj];
            y[t] = v; mx = fmaxf(mx, v);
        }
        mx = blockReduceMax(mx, red, tid);
        s = 0.f;
        #pragma unroll
        for (int t = 0; t < 4; ++t) { y[t] = __expf(y[t] - mx); s += y[t]; }
        s = blockReduceSum(s, red, tid);
        inv = 1.f / s;
        #pragma unroll
        for (int t = 0; t < 4; ++t) rowP[512 + tid + t * 256] = f2bf(y[t] * inv);
    }
}

// ============ host side ============

extern "C" void kernel_launch(void* const* d_in, const int* in_sizes, int n_in,
                              void* d_out, int out_size, void* d_ws, size_t ws_size,
                              hipStream_t stream)
{
    const int Bn = 4, Lt = 1024, Lh = 512;
    const float scale = 0.05103103630798288f;  // 1/sqrt(384)

    const float* text    = (const float*)d_in[0];
    const float* html    = (const float*)d_in[1];
    const int*   H2Hmask = (const int*)  d_in[2];
    const float* T2Tmask = (const float*)d_in[3];
    const float* H2Tmask = (const float*)d_in[4];
    const float* posemb  = (const float*)d_in[6];
    const float* edgeemb = (const float*)d_in[7];
    float* out = (float*)d_out;

    // ---- workspace carve (256B-aligned) ----
    char* p = (char*)d_ws;
    auto au16 = [&](long n) { u16* r = (u16*)p;  p += ((n * 2 + 255) & ~255L); return r; };
    auto af32 = [&](long n) { float* r = (float*)p; p += ((n * 4 + 255) & ~255L); return r; };

    const long nT = (long)Bn * Lt * 384;  // 1572864
    const long nH = (long)Bn * Lh * 384;  //  786432
    u16* text_bf = au16(nT);
    u16* html_bf = au16(nH);
    u16* WTtext  = au16(5L * 384 * 384);  // [1920][384]: V_T,K_H2T,Q_T2H,Q_T2T,K_T2T
    u16* WThtml  = au16(5L * 384 * 384);  // [1920][384]: V_H,Q_H2H,K_H2H,Q_H2T,K_T2H
    u16* edge_bf = au16(128L * 384);      // rows 0-63 valid, rest pad
    u16* pos_bf  = au16(128L * 384);      // rows 0-12 valid, rest pad
    u16* textQK  = au16((long)Bn * Lt * 1536);
    u16* htmlQK  = au16((long)Bn * Lh * 1536);
    u16* VTs     = au16((long)Bn * 384 * 1536);  // [b][384][html_v^T | text_v^T]
    float* qe = af32((long)Bn * Lh * 128);       // ldc 128, cols 0-63 valid
    float* qp = af32((long)Bn * Lt * 128);       // ldc 128, cols 0-12 valid
    float* scoresH = af32((long)Bn * Lh * 1536); // [b][512][h2h(512)|h2t(1024)]
    float* scoresT = af32((long)Bn * Lt * 1536); // [b][1024][t2h(512)|t2t(1024)]
    u16* probsH = au16((long)Bn * Lh * 1536);
    u16* probsT = au16((long)Bn * Lt * 1536);

    // ---- 1-2: conversions ----
    cvt4<<<2048, 256, 0, stream>>>((const float4*)text, (int)(nT / 4),
                                   (const float4*)html, (int)(nH / 4),
                                   (const float4*)edgeemb, 64 * 384 / 4,
                                   (const float4*)posemb, 13 * 384 / 4,
                                   text_bf, html_bf, edge_bf, pos_bf);
    WP wp; WD wd;
    for (int i = 0; i < 10; ++i) wp.p[i] = (const float*)d_in[8 + i];
    const long WSZ = 147456;  // 384*384
    wd.d[0] = WTtext + 0 * WSZ;  // W_V_T
    wd.d[1] = WThtml + 0 * WSZ;  // W_V_H
    wd.d[2] = WThtml + 1 * WSZ;  // W_Q_H2H
    wd.d[3] = WThtml + 2 * WSZ;  // W_K_H2H
    wd.d[4] = WThtml + 3 * WSZ;  // W_Q_H2T
    wd.d[5] = WTtext + 1 * WSZ;  // W_K_H2T
    wd.d[6] = WTtext + 2 * WSZ;  // W_Q_T2H
    wd.d[7] = WThtml + 4 * WSZ;  // W_K_T2H
    wd.d[8] = WTtext + 3 * WSZ;  // W_Q_T2T
    wd.d[9] = WTtext + 4 * WSZ;  // W_K_T2T
    wtrans<<<dim3(12, 12, 10), dim3(32, 32), 0, stream>>>(wp, wd);

    // packed QK column offsets
    u16* h2h_q = htmlQK + 0;     u16* h2h_k = htmlQK + 384;
    u16* h2t_q = htmlQK + 768;   u16* t2h_k = htmlQK + 1152;
    u16* h2t_k = textQK + 0;     u16* t2h_q = textQK + 384;
    u16* t2t_q = textQK + 768;   u16* t2t_k = textQK + 1152;

    // ---- 3: grouped projections at 128^2 (text 32x15=480, html 16x15=240) ----
    PSegs pj;
    pj.s[0] = { text_bf, WTtext, textQK, VTs, 10, 512, 32, 5, 0,   0 };
    pj.s[1] = { html_bf, WThtml, htmlQK, VTs,  9,   0, 16, 4, 480, 0 };
    proj_grouped<<<720, 256, 0, stream>>>(pj);

    const long sQt = (long)Lt * 1536, sQh = (long)Lh * 1536;
    const long sSh = (long)Lh * 1536, sSt = (long)Lt * 1536;
    const long sV  = (long)384 * 1536;
    const long sOut = (long)(Lt + Lh) * 384;

    // ---- 4: grouped scores + bias tables (156 xy-blocks x 4 batches) ----
    Segs sc;
    sc.s[0] = { h2h_q, h2h_k,  scoresH,       sQh, sQh, sSh, 1536, 1536, 1536, 384, 4, 2,   0, 0 }; // 16
    sc.s[1] = { h2t_q, h2t_k,  scoresH + 512, sQh, sQt, sSh, 1536, 1536, 1536, 384, 4, 2,  16, 0 }; // 32
    sc.s[2] = { t2h_q, t2h_k,  scoresT,       sQt, sQh, sSt, 1536, 1536, 1536, 384, 8, 3,  48, 0 }; // 32
    sc.s[3] = { t2t_q, t2t_k,  scoresT + 512, sQt, sQt, sSt, 1536, 1536, 1536, 384, 8, 3,  80, 0 }; // 64
    sc.s[4] = { h2h_q, edge_bf, qe,           sQh, 0,   (long)Lh * 128, 1536, 384, 128, 384, 4, 2, 144, 0 }; // 4
    sc.s[5] = { t2t_q, pos_bf,  qp,           sQt, 0,   (long)Lt * 128, 1536, 384, 128, 384, 8, 3, 148, 0 }; // 8
    sc.s[6] = sc.s[5]; sc.s[7] = sc.s[5];  // unused (NSEG=6)
    gemm_grouped<6, false><<<dim3(156, 4), 256, 0, stream>>>(sc);

    // ---- 5: fused softmax (2048 html rows + 4096 text rows) ----
    softmax_fused<<<6144, 256, 0, stream>>>(scoresH, probsH, scoresT, probsT,
                                            qe, qp, H2Hmask, H2Tmask, T2Tmask,
                                            scale);

    // ---- 6: zero output, then grouped PV with split-K x4 (144 xy x 4 batches) ----
    // Split-K: K=1536 -> 4 chunks of 384; each chunk atomic-adds its partial.
    // 576 blocks total (2.25/CU) vs round-7's 144 (0.56/CU, the 41us dispatch).
    hipMemsetAsync(out, 0, (size_t)out_size * sizeof(float), stream);
    float* outH = out + (long)Lt * 384;
    Segs pv;
    pv.s[0] = { probsH, VTs, outH, sQh, sV, sOut, 1536, 1536, 384, 384, 4, 2,   0, 0    }; // 12
    pv.s[1] = { probsH, VTs, outH, sQh, sV, sOut, 1536, 1536, 384, 384, 4, 2,  12, 384  }; // 12
    pv.s[2] = { probsH, VTs, outH, sQh, sV, sOut, 1536, 1536, 384, 384, 4, 2,  24, 768  }; // 12
    pv.s[3] = { probsH, VTs, outH, sQh, sV, sOut, 1536, 1536, 384, 384, 4, 2,  36, 1152 }; // 12
    pv.s[4] = { probsT, VTs, out,  sQt, sV, sOut, 1536, 1536, 384, 384, 8, 3,  48, 0    }; // 24
    pv.s[5] = { probsT, VTs, out,  sQt, sV, sOut, 1536, 1536, 384, 384, 8, 3,  72, 384  }; // 24
    pv.s[6] = { probsT, VTs, out,  sQt, sV, sOut, 1536, 1536, 384, 384, 8, 3,  96, 768  }; // 24
    pv.s[7] = { probsT, VTs, out,  sQt, sV, sOut, 1536, 1536, 384, 384, 8, 3, 120, 1152 }; // 24
    gemm_grouped<8, true><<<dim3(144, 4), 256, 0, stream>>>(pv);
}

// Round 10
// 206.015 us; speedup vs baseline: 1.0568x; 1.0568x over previous
//
#include <hip/hip_runtime.h>
#include <math.h>

typedef unsigned short u16;
typedef unsigned int u32;
typedef __attribute__((ext_vector_type(8))) short short8;
typedef __attribute__((ext_vector_type(4))) float f32x4;

__device__ __forceinline__ u16 f2bf(float f) {
    u32 u = __float_as_uint(f);
    u = (u + 0x7FFFu + ((u >> 16) & 1u)) >> 16;   // RNE
    return (u16)u;
}
__device__ __forceinline__ float bf2f(u16 h) {
    return __uint_as_float(((u32)h) << 16);
}

// ============ conversion kernels ============

// fp32 -> bf16: text, html, edgeemb(64x384), posemb(13x384)
__global__ __launch_bounds__(256)
void cvt4(const float4* __restrict__ a, int na4,
          const float4* __restrict__ b, int nb4,
          const float4* __restrict__ c, int nc4,
          const float4* __restrict__ d, int nd4,
          u16* __restrict__ oa, u16* __restrict__ ob,
          u16* __restrict__ oc, u16* __restrict__ od)
{
    int idx = blockIdx.x * 256 + threadIdx.x;
    const int tot = na4 + nb4 + nc4 + nd4;
    for (; idx < tot; idx += gridDim.x * 256) {
        float4 v; u16* o;
        int t = idx;
        if (t < na4)      { v = a[t]; o = oa + (long)t * 4; }
        else if ((t -= na4) < nb4) { v = b[t]; o = ob + (long)t * 4; }
        else if ((t -= nb4) < nc4) { v = c[t]; o = oc + (long)t * 4; }
        else { t -= nc4;    v = d[t]; o = od + (long)t * 4; }
        u32 lo = (u32)f2bf(v.x) | ((u32)f2bf(v.y) << 16);
        u32 hi = (u32)f2bf(v.z) | ((u32)f2bf(v.w) << 16);
        uint2 pk; pk.x = lo; pk.y = hi;
        *reinterpret_cast<uint2*>(o) = pk;
    }
}

struct WP { const float* p[10]; };
struct WD { u16* d[10]; };

// W [384][384] fp32 -> W^T bf16 at per-weight destination
__global__ __launch_bounds__(1024)
void wtrans(WP w, WD wd)
{
    __shared__ float t[32][33];
    const int z = blockIdx.z;
    const float* W = w.p[z];
    const int k = blockIdx.x * 32 + threadIdx.y;   // row of W
    const int n = blockIdx.y * 32 + threadIdx.x;   // col of W
    t[threadIdx.y][threadIdx.x] = W[k * 384 + n];
    __syncthreads();
    const int no = blockIdx.y * 32 + threadIdx.y;
    const int ko = blockIdx.x * 32 + threadIdx.x;
    wd.d[z][no * 384 + ko] = f2bf(t[threadIdx.x][threadIdx.y]);
}

// ============ 128x128 MFMA NT core, 2-phase double-buffered prefetch ============
// r8 diagnosis: single-buffered core serialized {load-drain | compute} per
// K-step -> latency-bound at low blocks/CU (PV: MfmaUtil 5.7% at ANY grid).
// Fix (T3 minimal recipe): issue STAGE(t+1) into buf^1 BEFORE compute of buf t;
// the end-of-iter __syncthreads (drains vmcnt) now lands after compute covered
// most of the load latency. Schedule identical to r5's verified 64^2 core.
__device__ __forceinline__ void mfma_core128(
    const u16* __restrict__ A, int lda,
    const u16* __restrict__ B, int ldb, int K,
    u16 (&As)[2][4096], u16 (&Bs)[2][4096],
    f32x4 (&acc)[4][4])
{
    const int tid  = threadIdx.x;
    const int wid  = tid >> 6;
    const int lane = tid & 63;
    const int wr = wid >> 1, wc = wid & 1;
    const int lane15 = lane & 15;
    const int kg = (lane >> 4) * 8;          // k offset of this lane's fragment
    const int srow = lane >> 2;              // staging row within 16-row group
    const int scol = (lane & 3) * 8;         // staging col (8 bf16 = 16B)

    #pragma unroll
    for (int i = 0; i < 4; ++i)
        #pragma unroll
        for (int j = 0; j < 4; ++j)
            acc[i][j] = (f32x4){0.f, 0.f, 0.f, 0.f};

    auto stage = [&](const u16* __restrict__ G, int ld, int k0, u16* lds) {
        #pragma unroll
        for (int i = 0; i < 2; ++i) {
            const int rg = (wid * 2 + i) * 16;
            const u16* g = G + (long)(rg + srow) * ld + (k0 + scol);
            u16* l = lds + (wid * 2 + i) * 512;   // wave-uniform base
            __builtin_amdgcn_global_load_lds(
                (const __attribute__((address_space(1))) void*)g,
                (__attribute__((address_space(3))) void*)l, 16, 0, 0);
        }
    };

    stage(A, lda, 0, As[0]);
    stage(B, ldb, 0, Bs[0]);
    __syncthreads();                          // tile 0 resident

    const int nt = K >> 5;
    int cur = 0;
    for (int t = 0; t < nt; ++t) {
        if (t + 1 < nt) {                     // prefetch next tile into buf^1
            stage(A, lda, (t + 1) << 5, As[cur ^ 1]);
            stage(B, ldb, (t + 1) << 5, Bs[cur ^ 1]);
        }
        short8 af[4], bf[4];
        #pragma unroll
        for (int mi = 0; mi < 4; ++mi)
            af[mi] = *reinterpret_cast<const short8*>(
                As[cur] + (wr * 64 + mi * 16 + lane15) * 32 + kg);
        #pragma unroll
        for (int ni = 0; ni < 4; ++ni)
            bf[ni] = *reinterpret_cast<const short8*>(
                Bs[cur] + (wc * 64 + ni * 16 + lane15) * 32 + kg);
        #pragma unroll
        for (int mi = 0; mi < 4; ++mi)
            #pragma unroll
            for (int ni = 0; ni < 4; ++ni)
                acc[mi][ni] = __builtin_amdgcn_mfma_f32_16x16x32_bf16(
                    af[mi], bf[ni], acc[mi][ni], 0, 0, 0);
        __syncthreads();   // drains vmcnt (next tile) + lgkm (reads done)
        cur ^= 1;
    }
}

// ============ grouped f32-output GEMM (scores + bias tables / PV) ============
struct Seg {
    const u16* A; const u16* B; float* C;
    long sA, sB, sC;
    int lda, ldb, ldc, K, nbx, nbxSh, start, pad;
};
struct Segs { Seg s[6]; };

template<int NSEG>
__global__ __launch_bounds__(256)
void gemm_grouped(Segs d)
{
    __shared__ __align__(16) u16 As[2][4096];
    __shared__ __align__(16) u16 Bs[2][4096];
    const int bid = blockIdx.x;
    Seg sg = d.s[0];                         // static-index selects only
    if (NSEG > 1 && bid >= d.s[1].start) sg = d.s[1];
    if (NSEG > 2 && bid >= d.s[2].start) sg = d.s[2];
    if (NSEG > 3 && bid >= d.s[3].start) sg = d.s[3];
    if (NSEG > 4 && bid >= d.s[4].start) sg = d.s[4];
    if (NSEG > 5 && bid >= d.s[5].start) sg = d.s[5];

    const int local = bid - sg.start;
    const int bx = local & (sg.nbx - 1);
    const int by = local >> sg.nbxSh;
    const int z  = blockIdx.y;
    const int m0 = bx * 128, n0 = by * 128;

    const u16* A = sg.A + (long)z * sg.sA + (long)m0 * sg.lda;
    const u16* B = sg.B + (long)z * sg.sB + (long)n0 * sg.ldb;

    f32x4 acc[4][4];
    mfma_core128(A, sg.lda, B, sg.ldb, sg.K, As, Bs, acc);

    const int tid = threadIdx.x;
    const int wid = tid >> 6, lane = tid & 63;
    const int wr = wid >> 1, wc = wid & 1;
    const int lane15 = lane & 15;
    const int r0 = (lane >> 4) * 4;

    // C/D frag: col = lane&15, row = (lane>>4)*4 + reg  [m89]
    float* C = sg.C + (long)z * sg.sC;
    #pragma unroll
    for (int mi = 0; mi < 4; ++mi)
        #pragma unroll
        for (int r = 0; r < 4; ++r) {
            const int row = m0 + wr * 64 + mi * 16 + r0 + r;
            float* crow = C + (long)row * sg.ldc + n0 + wc * 64 + lane15;
            #pragma unroll
            for (int ni = 0; ni < 4; ++ni)
                crow[ni * 16] = acc[mi][ni][r];
        }
}

// ============ grouped projection GEMM (V^T + packed QK epilogue) ============
struct PSeg {
    const u16* A; const u16* Bw; u16* QK; u16* VT;
    int lvtSh, vtOff, nbx, nbxSh, start, pad;
};
struct PSegs { PSeg s[2]; };

__global__ __launch_bounds__(256)
void proj_grouped(PSegs d)
{
    __shared__ __align__(16) u16 As[2][4096];
    __shared__ __align__(16) u16 Bs[2][4096];
    const int bid = blockIdx.x;
    PSeg sg = d.s[0];
    if (bid >= d.s[1].start) sg = d.s[1];

    const int local = bid - sg.start;
    const int bx = local & (sg.nbx - 1);
    const int by = local >> sg.nbxSh;
    const int m0 = bx * 128, n0 = by * 128;

    const u16* A = sg.A + (long)m0 * 384;
    const u16* B = sg.Bw + (long)n0 * 384;

    f32x4 acc[4][4];
    mfma_core128(A, 384, B, 384, 384, As, Bs, acc);

    const int tid = threadIdx.x;
    const int wid = tid >> 6, lane = tid & 63;
    const int wr = wid >> 1, wc = wid & 1;
    const int lane15 = lane & 15;
    const int r0 = (lane >> 4) * 4;
    const int lmask = (1 << sg.lvtSh) - 1;

    if (n0 < 384) {
        // V columns -> stacked transposed bf16: VT[(bz*384+col)*1536 + vtOff + l]
        #pragma unroll
        for (int mi = 0; mi < 4; ++mi) {
            const int row = m0 + wr * 64 + mi * 16 + r0;
            const int bz = row >> sg.lvtSh;
            const int l  = row & lmask;
            #pragma unroll
            for (int ni = 0; ni < 4; ++ni) {
                const int col = n0 + wc * 64 + ni * 16 + lane15;
                u32 lo = (u32)f2bf(acc[mi][ni][0]) | ((u32)f2bf(acc[mi][ni][1]) << 16);
                u32 hi = (u32)f2bf(acc[mi][ni][2]) | ((u32)f2bf(acc[mi][ni][3]) << 16);
                uint2 pk; pk.x = lo; pk.y = hi;
                *reinterpret_cast<uint2*>(
                    sg.VT + ((long)bz * 384 + col) * 1536 + sg.vtOff + l) = pk;
            }
        }
    } else {
        // Q/K columns -> packed bf16 [row][1536]
        #pragma unroll
        for (int mi = 0; mi < 4; ++mi)
            #pragma unroll
            for (int r = 0; r < 4; ++r) {
                const int row = m0 + wr * 64 + mi * 16 + r0 + r;
                u16* qrow = sg.QK + (long)row * 1536 + (n0 - 384) + wc * 64 + lane15;
                #pragma unroll
                for (int ni = 0; ni < 4; ++ni)
                    qrow[ni * 16] = f2bf(acc[mi][ni][r]);
            }
    }
}

// ============ fused softmax: one block per output row, two segments ============

__device__ __forceinline__ float blockReduceMax(float v, float* red, int tid) {
    #pragma unroll
    for (int o = 32; o >= 1; o >>= 1) v = fmaxf(v, __shfl_xor(v, o));
    if ((tid & 63) == 0) red[tid >> 6] = v;
    __syncthreads();
    return fmaxf(fmaxf(red[0], red[1]), fmaxf(red[2], red[3]));
}
__device__ __forceinline__ float blockReduceSum(float v, float* red, int tid) {
    #pragma unroll
    for (int o = 32; o >= 1; o >>= 1) v += __shfl_xor(v, o);
    if ((tid & 63) == 0) red[4 + (tid >> 6)] = v;
    __syncthreads();
    return red[4] + red[5] + red[6] + red[7];
}

// blocks 0..2047: html rows (h2h cols 0-511, h2t cols 512-1535)
// blocks 2048..6143: text rows (t2h cols 0-511, t2t cols 512-1535)
__global__ __launch_bounds__(256)
void softmax_fused(const float* __restrict__ scoresH, u16* __restrict__ probsH,
                   const float* __restrict__ scoresT, u16* __restrict__ probsT,
                   const float* __restrict__ qe, const float* __restrict__ qp,
                   const int* __restrict__ H2Hmask,
                   const float* __restrict__ H2Tmask,
                   const float* __restrict__ T2Tmask, float scale)
{
    const int bid = blockIdx.x;
    const int tid = threadIdx.x;
    __shared__ float qsh[64];
    __shared__ float red[8];

    if (bid < 2048) {
        const int b = bid >> 9, i = bid & 511;
        const long rbase = ((long)b * 512 + i) * 1536;
        const float* rowS = scoresH + rbase;
        u16* rowP = probsH + rbase;
        const int*   mrow  = H2Hmask + ((long)b * 512 + i) * 512;
        const float* m2row = H2Tmask + ((long)b * 512 + i) * 1024;
        if (tid < 64) qsh[tid] = qe[((long)b * 512 + i) * 128 + tid];
        __syncthreads();

        // --- h2h (512) ---
        float x[2]; float mx = -1e30f;
        #pragma unroll
        for (int t = 0; t < 2; ++t) {
            const int j = tid + t * 256;
            const int m = mrow[j];
            float v = (rowS[j] + qsh[m]) * scale - 10000.f * (m == 0 ? 1.f : 0.f);
            x[t] = v; mx = fmaxf(mx, v);
        }
        mx = blockReduceMax(mx, red, tid);
        float s = 0.f;
        #pragma unroll
        for (int t = 0; t < 2; ++t) { x[t] = __expf(x[t] - mx); s += x[t]; }
        s = blockReduceSum(s, red, tid);
        float inv = 1.f / s;
        #pragma unroll
        for (int t = 0; t < 2; ++t) rowP[tid + t * 256] = f2bf(x[t] * inv);

        // --- h2t (1024, cols 512..1535) ---
        float y[4]; mx = -1e30f;
        #pragma unroll
        for (int t = 0; t < 4; ++t) {
            const int jj = tid + t * 256;
            float v = rowS[512 + jj] * scale - 10000.f * m2row[jj];
            y[t] = v; mx = fmaxf(mx, v);
        }
        mx = blockReduceMax(mx, red, tid);
        s = 0.f;
        #pragma unroll
        for (int t = 0; t < 4; ++t) { y[t] = __expf(y[t] - mx); s += y[t]; }
        s = blockReduceSum(s, red, tid);
        inv = 1.f / s;
        #pragma unroll
        for (int t = 0; t < 4; ++t) rowP[512 + tid + t * 256] = f2bf(y[t] * inv);
    } else {
        const int bid2 = bid - 2048;
        const int b = bid2 >> 10, i = bid2 & 1023;
        const long rbase = ((long)b * 1024 + i) * 1536;
        const float* rowS = scoresT + rbase;
        u16* rowP = probsT + rbase;
        const float* m2row = T2Tmask + ((long)b * 1024 + i) * 1024;
        if (tid < 13) qsh[tid] = qp[((long)b * 1024 + i) * 128 + tid];
        __syncthreads();

        // --- t2h (512, no mask) ---
        float x[2]; float mx = -1e30f;
        #pragma unroll
        for (int t = 0; t < 2; ++t) {
            const int j = tid + t * 256;
            float v = rowS[j] * scale;
            x[t] = v; mx = fmaxf(mx, v);
        }
        mx = blockReduceMax(mx, red, tid);
        float s = 0.f;
        #pragma unroll
        for (int t = 0; t < 2; ++t) { x[t] = __expf(x[t] - mx); s += x[t]; }
        s = blockReduceSum(s, red, tid);
        float inv = 1.f / s;
        #pragma unroll
        for (int t = 0; t < 2; ++t) rowP[tid + t * 256] = f2bf(x[t] * inv);

        // --- t2t (1024, cols 512..1535) ---
        float y[4]; mx = -1e30f;
        #pragma unroll
        for (int t = 0; t < 4; ++t) {
            const int jj = tid + t * 256;
            int pos = jj - i;
            pos = (pos < -6 ? -6 : (pos > 6 ? 6 : pos)) + 6;
            float v = (rowS[512 + jj] + qsh[pos]) * scale - 10000.f * m2row[jj];
            y[t] = v; mx = fmaxf(mx, v);
        }
        mx = blockReduceMax(mx, red, tid);
        s = 0.f;
        #pragma unroll
        for (int t = 0; t < 4; ++t) { y[t] = __expf(y[t] - mx); s += y[t]; }
        s = blockReduceSum(s, red, tid);
        inv = 1.f / s;
        #pragma unroll
        for (int t = 0; t < 4; ++t) rowP[512 + tid + t * 256] = f2bf(y[t] * inv);
    }
}

// ============ host side ============

extern "C" void kernel_launch(void* const* d_in, const int* in_sizes, int n_in,
                              void* d_out, int out_size, void* d_ws, size_t ws_size,
                              hipStream_t stream)
{
    const int Bn = 4, Lt = 1024, Lh = 512;
    const float scale = 0.05103103630798288f;  // 1/sqrt(384)

    const float* text    = (const float*)d_in[0];
    const float* html    = (const float*)d_in[1];
    const int*   H2Hmask = (const int*)  d_in[2];
    const float* T2Tmask = (const float*)d_in[3];
    const float* H2Tmask = (const float*)d_in[4];
    const float* posemb  = (const float*)d_in[6];
    const float* edgeemb = (const float*)d_in[7];
    float* out = (float*)d_out;

    // ---- workspace carve (256B-aligned) ----
    char* p = (char*)d_ws;
    auto au16 = [&](long n) { u16* r = (u16*)p;  p += ((n * 2 + 255) & ~255L); return r; };
    auto af32 = [&](long n) { float* r = (float*)p; p += ((n * 4 + 255) & ~255L); return r; };

    const long nT = (long)Bn * Lt * 384;  // 1572864
    const long nH = (long)Bn * Lh * 384;  //  786432
    u16* text_bf = au16(nT);
    u16* html_bf = au16(nH);
    u16* WTtext  = au16(5L * 384 * 384);  // [1920][384]: V_T,K_H2T,Q_T2H,Q_T2T,K_T2T
    u16* WThtml  = au16(5L * 384 * 384);  // [1920][384]: V_H,Q_H2H,K_H2H,Q_H2T,K_T2H
    u16* edge_bf = au16(128L * 384);      // rows 0-63 valid, rest pad
    u16* pos_bf  = au16(128L * 384);      // rows 0-12 valid, rest pad
    u16* textQK  = au16((long)Bn * Lt * 1536);
    u16* htmlQK  = au16((long)Bn * Lh * 1536);
    u16* VTs     = au16((long)Bn * 384 * 1536);  // [b][384][html_v^T | text_v^T]
    float* qe = af32((long)Bn * Lh * 128);       // ldc 128, cols 0-63 valid
    float* qp = af32((long)Bn * Lt * 128);       // ldc 128, cols 0-12 valid
    float* scoresH = af32((long)Bn * Lh * 1536); // [b][512][h2h(512)|h2t(1024)]
    float* scoresT = af32((long)Bn * Lt * 1536); // [b][1024][t2h(512)|t2t(1024)]
    u16* probsH = au16((long)Bn * Lh * 1536);
    u16* probsT = au16((long)Bn * Lt * 1536);

    // ---- 1-2: conversions ----
    cvt4<<<2048, 256, 0, stream>>>((const float4*)text, (int)(nT / 4),
                                   (const float4*)html, (int)(nH / 4),
                                   (const float4*)edgeemb, 64 * 384 / 4,
                                   (const float4*)posemb, 13 * 384 / 4,
                                   text_bf, html_bf, edge_bf, pos_bf);
    WP wp; WD wd;
    for (int i = 0; i < 10; ++i) wp.p[i] = (const float*)d_in[8 + i];
    const long WSZ = 147456;  // 384*384
    wd.d[0] = WTtext + 0 * WSZ;  // W_V_T
    wd.d[1] = WThtml + 0 * WSZ;  // W_V_H
    wd.d[2] = WThtml + 1 * WSZ;  // W_Q_H2H
    wd.d[3] = WThtml + 2 * WSZ;  // W_K_H2H
    wd.d[4] = WThtml + 3 * WSZ;  // W_Q_H2T
    wd.d[5] = WTtext + 1 * WSZ;  // W_K_H2T
    wd.d[6] = WTtext + 2 * WSZ;  // W_Q_T2H
    wd.d[7] = WThtml + 4 * WSZ;  // W_K_T2H
    wd.d[8] = WTtext + 3 * WSZ;  // W_Q_T2T
    wd.d[9] = WTtext + 4 * WSZ;  // W_K_T2T
    wtrans<<<dim3(12, 12, 10), dim3(32, 32), 0, stream>>>(wp, wd);

    // packed QK column offsets
    u16* h2h_q = htmlQK + 0;     u16* h2h_k = htmlQK + 384;
    u16* h2t_q = htmlQK + 768;   u16* t2h_k = htmlQK + 1152;
    u16* h2t_k = textQK + 0;     u16* t2h_q = textQK + 384;
    u16* t2t_q = textQK + 768;   u16* t2t_k = textQK + 1152;

    // ---- 3: grouped projections at 128^2 (text 32x15=480, html 16x15=240) ----
    PSegs pj;
    pj.s[0] = { text_bf, WTtext, textQK, VTs, 10, 512, 32, 5, 0,   0 };
    pj.s[1] = { html_bf, WThtml, htmlQK, VTs,  9,   0, 16, 4, 480, 0 };
    proj_grouped<<<720, 256, 0, stream>>>(pj);

    const long sQt = (long)Lt * 1536, sQh = (long)Lh * 1536;
    const long sSh = (long)Lh * 1536, sSt = (long)Lt * 1536;
    const long sV  = (long)384 * 1536;
    const long sOut = (long)(Lt + Lh) * 384;

    // ---- 4: grouped scores + bias tables (156 xy-blocks x 4 batches) ----
    Segs sc;
    sc.s[0] = { h2h_q, h2h_k,  scoresH,       sQh, sQh, sSh, 1536, 1536, 1536, 384, 4, 2,   0, 0 }; // 16
    sc.s[1] = { h2t_q, h2t_k,  scoresH + 512, sQh, sQt, sSh, 1536, 1536, 1536, 384, 4, 2,  16, 0 }; // 32
    sc.s[2] = { t2h_q, t2h_k,  scoresT,       sQt, sQh, sSt, 1536, 1536, 1536, 384, 8, 3,  48, 0 }; // 32
    sc.s[3] = { t2t_q, t2t_k,  scoresT + 512, sQt, sQt, sSt, 1536, 1536, 1536, 384, 8, 3,  80, 0 }; // 64
    sc.s[4] = { h2h_q, edge_bf, qe,           sQh, 0,   (long)Lh * 128, 1536, 384, 128, 384, 4, 2, 144, 0 }; // 4
    sc.s[5] = { t2t_q, pos_bf,  qp,           sQt, 0,   (long)Lt * 128, 1536, 384, 128, 384, 8, 3, 148, 0 }; // 8
    gemm_grouped<6><<<dim3(156, 4), 256, 0, stream>>>(sc);

    // ---- 5: fused softmax (2048 html rows + 4096 text rows) ----
    softmax_fused<<<6144, 256, 0, stream>>>(scoresH, probsH, scoresT, probsT,
                                            qe, qp, H2Hmask, H2Tmask, T2Tmask,
                                            scale);

    // ---- 6: grouped PV GEMMs at 128^2 (K=1536 stacked V; r7 config) ----
    Segs pv;
    pv.s[0] = { probsH, VTs, out + (long)Lt * 384, sQh, sV, sOut, 1536, 1536, 384, 1536, 4, 2,  0, 0 }; // 12
    pv.s[1] = { probsT, VTs, out,                  sQt, sV, sOut, 1536, 1536, 384, 1536, 8, 3, 12, 0 }; // 24
    pv.s[2] = pv.s[1]; pv.s[3] = pv.s[1]; pv.s[4] = pv.s[1]; pv.s[5] = pv.s[1];
    gemm_grouped<2><<<dim3(36, 4), 256, 0, stream>>>(pv);
}

// Round 11
// 189.983 us; speedup vs baseline: 1.1459x; 1.0844x over previous
//
#include <hip/hip_runtime.h>
#include <math.h>

typedef unsigned short u16;
typedef unsigned int u32;
typedef __attribute__((ext_vector_type(8))) short short8;
typedef __attribute__((ext_vector_type(4))) float f32x4;

__device__ __forceinline__ u16 f2bf(float f) {
    u32 u = __float_as_uint(f);
    u = (u + 0x7FFFu + ((u >> 16) & 1u)) >> 16;   // RNE
    return (u16)u;
}
__device__ __forceinline__ float bf2f(u16 h) {
    return __uint_as_float(((u32)h) << 16);
}

// ============ conversion kernels ============

// fp32 -> bf16: text, html, edgeemb(64x384), posemb(13x384)
__global__ __launch_bounds__(256)
void cvt4(const float4* __restrict__ a, int na4,
          const float4* __restrict__ b, int nb4,
          const float4* __restrict__ c, int nc4,
          const float4* __restrict__ d, int nd4,
          u16* __restrict__ oa, u16* __restrict__ ob,
          u16* __restrict__ oc, u16* __restrict__ od)
{
    int idx = blockIdx.x * 256 + threadIdx.x;
    const int tot = na4 + nb4 + nc4 + nd4;
    for (; idx < tot; idx += gridDim.x * 256) {
        float4 v; u16* o;
        int t = idx;
        if (t < na4)      { v = a[t]; o = oa + (long)t * 4; }
        else if ((t -= na4) < nb4) { v = b[t]; o = ob + (long)t * 4; }
        else if ((t -= nb4) < nc4) { v = c[t]; o = oc + (long)t * 4; }
        else { t -= nc4;    v = d[t]; o = od + (long)t * 4; }
        u32 lo = (u32)f2bf(v.x) | ((u32)f2bf(v.y) << 16);
        u32 hi = (u32)f2bf(v.z) | ((u32)f2bf(v.w) << 16);
        uint2 pk; pk.x = lo; pk.y = hi;
        *reinterpret_cast<uint2*>(o) = pk;
    }
}

struct WP { const float* p[10]; };
struct WD { u16* d[10]; };

// W [384][384] fp32 -> W^T bf16 at per-weight destination
__global__ __launch_bounds__(1024)
void wtrans(WP w, WD wd)
{
    __shared__ float t[32][33];
    const int z = blockIdx.z;
    const float* W = w.p[z];
    const int k = blockIdx.x * 32 + threadIdx.y;   // row of W
    const int n = blockIdx.y * 32 + threadIdx.x;   // col of W
    t[threadIdx.y][threadIdx.x] = W[k * 384 + n];
    __syncthreads();
    const int no = blockIdx.y * 32 + threadIdx.y;
    const int ko = blockIdx.x * 32 + threadIdx.x;
    wd.d[z][no * 384 + ko] = f2bf(t[threadIdx.x][threadIdx.y]);
}

// ============ 128x128 MFMA NT core, 2-phase double-buffered prefetch ============
__device__ __forceinline__ void mfma_core128(
    const u16* __restrict__ A, int lda,
    const u16* __restrict__ B, int ldb, int K,
    u16 (&As)[2][4096], u16 (&Bs)[2][4096],
    f32x4 (&acc)[4][4])
{
    const int tid  = threadIdx.x;
    const int wid  = tid >> 6;
    const int lane = tid & 63;
    const int wr = wid >> 1, wc = wid & 1;
    const int lane15 = lane & 15;
    const int kg = (lane >> 4) * 8;          // k offset of this lane's fragment
    const int srow = lane >> 2;              // staging row within 16-row group
    const int scol = (lane & 3) * 8;         // staging col (8 bf16 = 16B)

    #pragma unroll
    for (int i = 0; i < 4; ++i)
        #pragma unroll
        for (int j = 0; j < 4; ++j)
            acc[i][j] = (f32x4){0.f, 0.f, 0.f, 0.f};

    auto stage = [&](const u16* __restrict__ G, int ld, int k0, u16* lds) {
        #pragma unroll
        for (int i = 0; i < 2; ++i) {
            const int rg = (wid * 2 + i) * 16;
            const u16* g = G + (long)(rg + srow) * ld + (k0 + scol);
            u16* l = lds + (wid * 2 + i) * 512;   // wave-uniform base
            __builtin_amdgcn_global_load_lds(
                (const __attribute__((address_space(1))) void*)g,
                (__attribute__((address_space(3))) void*)l, 16, 0, 0);
        }
    };

    stage(A, lda, 0, As[0]);
    stage(B, ldb, 0, Bs[0]);
    __syncthreads();                          // tile 0 resident

    const int nt = K >> 5;
    int cur = 0;
    for (int t = 0; t < nt; ++t) {
        if (t + 1 < nt) {                     // prefetch next tile into buf^1
            stage(A, lda, (t + 1) << 5, As[cur ^ 1]);
            stage(B, ldb, (t + 1) << 5, Bs[cur ^ 1]);
        }
        short8 af[4], bf[4];
        #pragma unroll
        for (int mi = 0; mi < 4; ++mi)
            af[mi] = *reinterpret_cast<const short8*>(
                As[cur] + (wr * 64 + mi * 16 + lane15) * 32 + kg);
        #pragma unroll
        for (int ni = 0; ni < 4; ++ni)
            bf[ni] = *reinterpret_cast<const short8*>(
                Bs[cur] + (wc * 64 + ni * 16 + lane15) * 32 + kg);
        #pragma unroll
        for (int mi = 0; mi < 4; ++mi)
            #pragma unroll
            for (int ni = 0; ni < 4; ++ni)
                acc[mi][ni] = __builtin_amdgcn_mfma_f32_16x16x32_bf16(
                    af[mi], bf[ni], acc[mi][ni], 0, 0, 0);
        __syncthreads();   // drains vmcnt (next tile) + lgkm (reads done)
        cur ^= 1;
    }
}

// ============ 64x64 MFMA NT core (r5-verified: dbuf, BK=64, XOR swizzle) ======
// Bit-identical math to 128^2 core (ascending-K accumulation). Used for PV:
// 4x the blocks (576 vs 144 -> 2.25/CU) to supply inter-block latency overlap
// (m114 mechanism) that 0.56 blocks/CU cannot.
__device__ __forceinline__ void mfma_core64(
    const u16* __restrict__ A, int lda,
    const u16* __restrict__ B, int ldb, int K,
    u16 (&As)[2][4096], u16 (&Bs)[2][4096],
    f32x4 (&acc)[2][2])
{
    const int tid  = threadIdx.x;
    const int wid  = tid >> 6;
    const int lane = tid & 63;
    const int wr = wid >> 1, wc = wid & 1;
    const int lane15 = lane & 15;
    const int lq = lane >> 4;                // 0..3
    const int g0 = wid * 64 + lane;

    #pragma unroll
    for (int i = 0; i < 2; ++i)
        #pragma unroll
        for (int j = 0; j < 2; ++j)
            acc[i][j] = (f32x4){0.f, 0.f, 0.f, 0.f};

    auto stage = [&](const u16* __restrict__ G, int ld, int k0, u16* lds) {
        #pragma unroll
        for (int h = 0; h < 2; ++h) {
            const int gid  = g0 + h * 256;
            const int row  = gid >> 3;
            const int slot = (gid & 7) ^ (row & 7);     // pre-swizzled source
            const u16* src = G + (long)row * ld + k0 + slot * 8;
            u16* dst = lds + wid * 512 + h * 2048;      // wave-uniform base
            __builtin_amdgcn_global_load_lds(
                (const __attribute__((address_space(1))) void*)src,
                (__attribute__((address_space(3))) void*)dst, 16, 0, 0);
        }
    };
    auto rd = [&](const u16* lds, int row, int colslot) -> short8 {
        const int byt = row * 128 + ((colslot ^ (row & 7)) << 4);
        return *reinterpret_cast<const short8*>(
            reinterpret_cast<const char*>(lds) + byt);
    };

    stage(A, lda, 0, As[0]);
    stage(B, ldb, 0, Bs[0]);
    __syncthreads();

    const int nt = K >> 6;
    int cur = 0;
    for (int t = 0; t < nt; ++t) {
        if (t + 1 < nt) {                   // prefetch next tile into buf^1
            stage(A, lda, (t + 1) << 6, As[cur ^ 1]);
            stage(B, ldb, (t + 1) << 6, Bs[cur ^ 1]);
        }
        short8 af[2][2], bf[2][2];
        #pragma unroll
        for (int mi = 0; mi < 2; ++mi)
            #pragma unroll
            for (int kk = 0; kk < 2; ++kk)
                af[mi][kk] = rd(As[cur], wr * 32 + mi * 16 + lane15, kk * 4 + lq);
        #pragma unroll
        for (int ni = 0; ni < 2; ++ni)
            #pragma unroll
            for (int kk = 0; kk < 2; ++kk)
                bf[ni][kk] = rd(Bs[cur], wc * 32 + ni * 16 + lane15, kk * 4 + lq);
        #pragma unroll
        for (int mi = 0; mi < 2; ++mi)
            #pragma unroll
            for (int ni = 0; ni < 2; ++ni)
                #pragma unroll
                for (int kk = 0; kk < 2; ++kk)
                    acc[mi][ni] = __builtin_amdgcn_mfma_f32_16x16x32_bf16(
                        af[mi][kk], bf[ni][kk], acc[mi][ni], 0, 0, 0);
        __syncthreads();
        cur ^= 1;
    }
}

// ============ grouped GEMM descriptors ============
struct Seg {
    const u16* A; const u16* B; float* C;
    long sA, sB, sC;
    int lda, ldb, ldc, K, nbx, nbxSh, start, pad;
};
struct Segs { Seg s[6]; };

// 128^2 tiles: scores + bias tables
template<int NSEG>
__global__ __launch_bounds__(256)
void gemm_grouped(Segs d)
{
    __shared__ __align__(16) u16 As[2][4096];
    __shared__ __align__(16) u16 Bs[2][4096];
    const int bid = blockIdx.x;
    Seg sg = d.s[0];                         // static-index selects only
    if (NSEG > 1 && bid >= d.s[1].start) sg = d.s[1];
    if (NSEG > 2 && bid >= d.s[2].start) sg = d.s[2];
    if (NSEG > 3 && bid >= d.s[3].start) sg = d.s[3];
    if (NSEG > 4 && bid >= d.s[4].start) sg = d.s[4];
    if (NSEG > 5 && bid >= d.s[5].start) sg = d.s[5];

    const int local = bid - sg.start;
    const int bx = local & (sg.nbx - 1);
    const int by = local >> sg.nbxSh;
    const int z  = blockIdx.y;
    const int m0 = bx * 128, n0 = by * 128;

    const u16* A = sg.A + (long)z * sg.sA + (long)m0 * sg.lda;
    const u16* B = sg.B + (long)z * sg.sB + (long)n0 * sg.ldb;

    f32x4 acc[4][4];
    mfma_core128(A, sg.lda, B, sg.ldb, sg.K, As, Bs, acc);

    const int tid = threadIdx.x;
    const int wid = tid >> 6, lane = tid & 63;
    const int wr = wid >> 1, wc = wid & 1;
    const int lane15 = lane & 15;
    const int r0 = (lane >> 4) * 4;

    // C/D frag: col = lane&15, row = (lane>>4)*4 + reg  [m89]
    float* C = sg.C + (long)z * sg.sC;
    #pragma unroll
    for (int mi = 0; mi < 4; ++mi)
        #pragma unroll
        for (int r = 0; r < 4; ++r) {
            const int row = m0 + wr * 64 + mi * 16 + r0 + r;
            float* crow = C + (long)row * sg.ldc + n0 + wc * 64 + lane15;
            #pragma unroll
            for (int ni = 0; ni < 4; ++ni)
                crow[ni * 16] = acc[mi][ni][r];
        }
}

// 64^2 tiles: PV (occupancy-bound launch)
template<int NSEG>
__global__ __launch_bounds__(256)
void gemm_grouped64(Segs d)
{
    __shared__ __align__(16) u16 As[2][4096];
    __shared__ __align__(16) u16 Bs[2][4096];
    const int bid = blockIdx.x;
    Seg sg = d.s[0];
    if (NSEG > 1 && bid >= d.s[1].start) sg = d.s[1];

    const int local = bid - sg.start;
    const int bx = local & (sg.nbx - 1);
    const int by = local >> sg.nbxSh;
    const int z  = blockIdx.y;
    const int m0 = bx * 64, n0 = by * 64;

    const u16* A = sg.A + (long)z * sg.sA + (long)m0 * sg.lda;
    const u16* B = sg.B + (long)z * sg.sB + (long)n0 * sg.ldb;

    f32x4 acc[2][2];
    mfma_core64(A, sg.lda, B, sg.ldb, sg.K, As, Bs, acc);

    const int tid = threadIdx.x;
    const int wid = tid >> 6, lane = tid & 63;
    const int wr = wid >> 1, wc = wid & 1;
    const int lane15 = lane & 15;
    const int r0 = (lane >> 4) * 4;

    float* C = sg.C + (long)z * sg.sC;
    #pragma unroll
    for (int mi = 0; mi < 2; ++mi)
        #pragma unroll
        for (int r = 0; r < 4; ++r) {
            const int row = m0 + wr * 32 + mi * 16 + r0 + r;
            float* crow = C + (long)row * sg.ldc + n0 + wc * 32 + lane15;
            #pragma unroll
            for (int ni = 0; ni < 2; ++ni)
                crow[ni * 16] = acc[mi][ni][r];
        }
}

// ============ grouped projection GEMM (V^T + packed QK epilogue) ============
struct PSeg {
    const u16* A; const u16* Bw; u16* QK; u16* VT;
    int lvtSh, vtOff, nbx, nbxSh, start, pad;
};
struct PSegs { PSeg s[2]; };

__global__ __launch_bounds__(256)
void proj_grouped(PSegs d)
{
    __shared__ __align__(16) u16 As[2][4096];
    __shared__ __align__(16) u16 Bs[2][4096];
    const int bid = blockIdx.x;
    PSeg sg = d.s[0];
    if (bid >= d.s[1].start) sg = d.s[1];

    const int local = bid - sg.start;
    const int bx = local & (sg.nbx - 1);
    const int by = local >> sg.nbxSh;
    const int m0 = bx * 128, n0 = by * 128;

    const u16* A = sg.A + (long)m0 * 384;
    const u16* B = sg.Bw + (long)n0 * 384;

    f32x4 acc[4][4];
    mfma_core128(A, 384, B, 384, 384, As, Bs, acc);

    const int tid = threadIdx.x;
    const int wid = tid >> 6, lane = tid & 63;
    const int wr = wid >> 1, wc = wid & 1;
    const int lane15 = lane & 15;
    const int r0 = (lane >> 4) * 4;
    const int lmask = (1 << sg.lvtSh) - 1;

    if (n0 < 384) {
        // V columns -> stacked transposed bf16: VT[(bz*384+col)*1536 + vtOff + l]
        #pragma unroll
        for (int mi = 0; mi < 4; ++mi) {
            const int row = m0 + wr * 64 + mi * 16 + r0;
            const int bz = row >> sg.lvtSh;
            const int l  = row & lmask;
            #pragma unroll
            for (int ni = 0; ni < 4; ++ni) {
                const int col = n0 + wc * 64 + ni * 16 + lane15;
                u32 lo = (u32)f2bf(acc[mi][ni][0]) | ((u32)f2bf(acc[mi][ni][1]) << 16);
                u32 hi = (u32)f2bf(acc[mi][ni][2]) | ((u32)f2bf(acc[mi][ni][3]) << 16);
                uint2 pk; pk.x = lo; pk.y = hi;
                *reinterpret_cast<uint2*>(
                    sg.VT + ((long)bz * 384 + col) * 1536 + sg.vtOff + l) = pk;
            }
        }
    } else {
        // Q/K columns -> packed bf16 [row][1536]
        #pragma unroll
        for (int mi = 0; mi < 4; ++mi)
            #pragma unroll
            for (int r = 0; r < 4; ++r) {
                const int row = m0 + wr * 64 + mi * 16 + r0 + r;
                u16* qrow = sg.QK + (long)row * 1536 + (n0 - 384) + wc * 64 + lane15;
                #pragma unroll
                for (int ni = 0; ni < 4; ++ni)
                    qrow[ni * 16] = f2bf(acc[mi][ni][r]);
            }
    }
}

// ============ fused softmax: one block per output row, two segments ============

__device__ __forceinline__ float blockReduceMax(float v, float* red, int tid) {
    #pragma unroll
    for (int o = 32; o >= 1; o >>= 1) v = fmaxf(v, __shfl_xor(v, o));
    if ((tid & 63) == 0) red[tid >> 6] = v;
    __syncthreads();
    return fmaxf(fmaxf(red[0], red[1]), fmaxf(red[2], red[3]));
}
__device__ __forceinline__ float blockReduceSum(float v, float* red, int tid) {
    #pragma unroll
    for (int o = 32; o >= 1; o >>= 1) v += __shfl_xor(v, o);
    if ((tid & 63) == 0) red[4 + (tid >> 6)] = v;
    __syncthreads();
    return red[4] + red[5] + red[6] + red[7];
}

// blocks 0..2047: html rows (h2h cols 0-511, h2t cols 512-1535)
// blocks 2048..6143: text rows (t2h cols 0-511, t2t cols 512-1535)
__global__ __launch_bounds__(256)
void softmax_fused(const float* __restrict__ scoresH, u16* __restrict__ probsH,
                   const float* __restrict__ scoresT, u16* __restrict__ probsT,
                   const float* __restrict__ qe, const float* __restrict__ qp,
                   const int* __restrict__ H2Hmask,
                   const float* __restrict__ H2Tmask,
                   const float* __restrict__ T2Tmask, float scale)
{
    const int bid = blockIdx.x;
    const int tid = threadIdx.x;
    __shared__ float qsh[64];
    __shared__ float red[8];

    if (bid < 2048) {
        const int b = bid >> 9, i = bid & 511;
        const long rbase = ((long)b * 512 + i) * 1536;
        const float* rowS = scoresH + rbase;
        u16* rowP = probsH + rbase;
        const int*   mrow  = H2Hmask + ((long)b * 512 + i) * 512;
        const float* m2row = H2Tmask + ((long)b * 512 + i) * 1024;
        if (tid < 64) qsh[tid] = qe[((long)b * 512 + i) * 128 + tid];
        __syncthreads();

        // --- h2h (512) ---
        float x[2]; float mx = -1e30f;
        #pragma unroll
        for (int t = 0; t < 2; ++t) {
            const int j = tid + t * 256;
            const int m = mrow[j];
            float v = (rowS[j] + qsh[m]) * scale - 10000.f * (m == 0 ? 1.f : 0.f);
            x[t] = v; mx = fmaxf(mx, v);
        }
        mx = blockReduceMax(mx, red, tid);
        float s = 0.f;
        #pragma unroll
        for (int t = 0; t < 2; ++t) { x[t] = __expf(x[t] - mx); s += x[t]; }
        s = blockReduceSum(s, red, tid);
        float inv = 1.f / s;
        #pragma unroll
        for (int t = 0; t < 2; ++t) rowP[tid + t * 256] = f2bf(x[t] * inv);

        // --- h2t (1024, cols 512..1535) ---
        float y[4]; mx = -1e30f;
        #pragma unroll
        for (int t = 0; t < 4; ++t) {
            const int jj = tid + t * 256;
            float v = rowS[512 + jj] * scale - 10000.f * m2row[jj];
            y[t] = v; mx = fmaxf(mx, v);
        }
        mx = blockReduceMax(mx, red, tid);
        s = 0.f;
        #pragma unroll
        for (int t = 0; t < 4; ++t) { y[t] = __expf(y[t] - mx); s += y[t]; }
        s = blockReduceSum(s, red, tid);
        inv = 1.f / s;
        #pragma unroll
        for (int t = 0; t < 4; ++t) rowP[512 + tid + t * 256] = f2bf(y[t] * inv);
    } else {
        const int bid2 = bid - 2048;
        const int b = bid2 >> 10, i = bid2 & 1023;
        const long rbase = ((long)b * 1024 + i) * 1536;
        const float* rowS = scoresT + rbase;
        u16* rowP = probsT + rbase;
        const float* m2row = T2Tmask + ((long)b * 1024 + i) * 1024;
        if (tid < 13) qsh[tid] = qp[((long)b * 1024 + i) * 128 + tid];
        __syncthreads();

        // --- t2h (512, no mask) ---
        float x[2]; float mx = -1e30f;
        #pragma unroll
        for (int t = 0; t < 2; ++t) {
            const int j = tid + t * 256;
            float v = rowS[j] * scale;
            x[t] = v; mx = fmaxf(mx, v);
        }
        mx = blockReduceMax(mx, red, tid);
        float s = 0.f;
        #pragma unroll
        for (int t = 0; t < 2; ++t) { x[t] = __expf(x[t] - mx); s += x[t]; }
        s = blockReduceSum(s, red, tid);
        float inv = 1.f / s;
        #pragma unroll
        for (int t = 0; t < 2; ++t) rowP[tid + t * 256] = f2bf(x[t] * inv);

        // --- t2t (1024, cols 512..1535) ---
        float y[4]; mx = -1e30f;
        #pragma unroll
        for (int t = 0; t < 4; ++t) {
            const int jj = tid + t * 256;
            int pos = jj - i;
            pos = (pos < -6 ? -6 : (pos > 6 ? 6 : pos)) + 6;
            float v = (rowS[512 + jj] + qsh[pos]) * scale - 10000.f * m2row[jj];
            y[t] = v; mx = fmaxf(mx, v);
        }
        mx = blockReduceMax(mx, red, tid);
        s = 0.f;
        #pragma unroll
        for (int t = 0; t < 4; ++t) { y[t] = __expf(y[t] - mx); s += y[t]; }
        s = blockReduceSum(s, red, tid);
        inv = 1.f / s;
        #pragma unroll
        for (int t = 0; t < 4; ++t) rowP[512 + tid + t * 256] = f2bf(y[t] * inv);
    }
}

// ============ host side ============

extern "C" void kernel_launch(void* const* d_in, const int* in_sizes, int n_in,
                              void* d_out, int out_size, void* d_ws, size_t ws_size,
                              hipStream_t stream)
{
    const int Bn = 4, Lt = 1024, Lh = 512;
    const float scale = 0.05103103630798288f;  // 1/sqrt(384)

    const float* text    = (const float*)d_in[0];
    const float* html    = (const float*)d_in[1];
    const int*   H2Hmask = (const int*)  d_in[2];
    const float* T2Tmask = (const float*)d_in[3];
    const float* H2Tmask = (const float*)d_in[4];
    const float* posemb  = (const float*)d_in[6];
    const float* edgeemb = (const float*)d_in[7];
    float* out = (float*)d_out;

    // ---- workspace carve (256B-aligned) ----
    char* p = (char*)d_ws;
    auto au16 = [&](long n) { u16* r = (u16*)p;  p += ((n * 2 + 255) & ~255L); return r; };
    auto af32 = [&](long n) { float* r = (float*)p; p += ((n * 4 + 255) & ~255L); return r; };

    const long nT = (long)Bn * Lt * 384;  // 1572864
    const long nH = (long)Bn * Lh * 384;  //  786432
    u16* text_bf = au16(nT);
    u16* html_bf = au16(nH);
    u16* WTtext  = au16(5L * 384 * 384);  // [1920][384]: V_T,K_H2T,Q_T2H,Q_T2T,K_T2T
    u16* WThtml  = au16(5L * 384 * 384);  // [1920][384]: V_H,Q_H2H,K_H2H,Q_H2T,K_T2H
    u16* edge_bf = au16(128L * 384);      // rows 0-63 valid, rest pad
    u16* pos_bf  = au16(128L * 384);      // rows 0-12 valid, rest pad
    u16* textQK  = au16((long)Bn * Lt * 1536);
    u16* htmlQK  = au16((long)Bn * Lh * 1536);
    u16* VTs     = au16((long)Bn * 384 * 1536);  // [b][384][html_v^T | text_v^T]
    float* qe = af32((long)Bn * Lh * 128);       // ldc 128, cols 0-63 valid
    float* qp = af32((long)Bn * Lt * 128);       // ldc 128, cols 0-12 valid
    float* scoresH = af32((long)Bn * Lh * 1536); // [b][512][h2h(512)|h2t(1024)]
    float* scoresT = af32((long)Bn * Lt * 1536); // [b][1024][t2h(512)|t2t(1024)]
    u16* probsH = au16((long)Bn * Lh * 1536);
    u16* probsT = au16((long)Bn * Lt * 1536);

    // ---- 1-2: conversions ----
    cvt4<<<2048, 256, 0, stream>>>((const float4*)text, (int)(nT / 4),
                                   (const float4*)html, (int)(nH / 4),
                                   (const float4*)edgeemb, 64 * 384 / 4,
                                   (const float4*)posemb, 13 * 384 / 4,
                                   text_bf, html_bf, edge_bf, pos_bf);
    WP wp; WD wd;
    for (int i = 0; i < 10; ++i) wp.p[i] = (const float*)d_in[8 + i];
    const long WSZ = 147456;  // 384*384
    wd.d[0] = WTtext + 0 * WSZ;  // W_V_T
    wd.d[1] = WThtml + 0 * WSZ;  // W_V_H
    wd.d[2] = WThtml + 1 * WSZ;  // W_Q_H2H
    wd.d[3] = WThtml + 2 * WSZ;  // W_K_H2H
    wd.d[4] = WThtml + 3 * WSZ;  // W_Q_H2T
    wd.d[5] = WTtext + 1 * WSZ;  // W_K_H2T
    wd.d[6] = WTtext + 2 * WSZ;  // W_Q_T2H
    wd.d[7] = WThtml + 4 * WSZ;  // W_K_T2H
    wd.d[8] = WTtext + 3 * WSZ;  // W_Q_T2T
    wd.d[9] = WTtext + 4 * WSZ;  // W_K_T2T
    wtrans<<<dim3(12, 12, 10), dim3(32, 32), 0, stream>>>(wp, wd);

    // packed QK column offsets
    u16* h2h_q = htmlQK + 0;     u16* h2h_k = htmlQK + 384;
    u16* h2t_q = htmlQK + 768;   u16* t2h_k = htmlQK + 1152;
    u16* h2t_k = textQK + 0;     u16* t2h_q = textQK + 384;
    u16* t2t_q = textQK + 768;   u16* t2t_k = textQK + 1152;

    // ---- 3: grouped projections at 128^2 (text 32x15=480, html 16x15=240) ----
    PSegs pj;
    pj.s[0] = { text_bf, WTtext, textQK, VTs, 10, 512, 32, 5, 0,   0 };
    pj.s[1] = { html_bf, WThtml, htmlQK, VTs,  9,   0, 16, 4, 480, 0 };
    proj_grouped<<<720, 256, 0, stream>>>(pj);

    const long sQt = (long)Lt * 1536, sQh = (long)Lh * 1536;
    const long sSh = (long)Lh * 1536, sSt = (long)Lt * 1536;
    const long sV  = (long)384 * 1536;
    const long sOut = (long)(Lt + Lh) * 384;

    // ---- 4: grouped scores + bias tables (156 xy-blocks x 4 batches) ----
    Segs sc;
    sc.s[0] = { h2h_q, h2h_k,  scoresH,       sQh, sQh, sSh, 1536, 1536, 1536, 384, 4, 2,   0, 0 }; // 16
    sc.s[1] = { h2t_q, h2t_k,  scoresH + 512, sQh, sQt, sSh, 1536, 1536, 1536, 384, 4, 2,  16, 0 }; // 32
    sc.s[2] = { t2h_q, t2h_k,  scoresT,       sQt, sQh, sSt, 1536, 1536, 1536, 384, 8, 3,  48, 0 }; // 32
    sc.s[3] = { t2t_q, t2t_k,  scoresT + 512, sQt, sQt, sSt, 1536, 1536, 1536, 384, 8, 3,  80, 0 }; // 64
    sc.s[4] = { h2h_q, edge_bf, qe,           sQh, 0,   (long)Lh * 128, 1536, 384, 128, 384, 4, 2, 144, 0 }; // 4
    sc.s[5] = { t2t_q, pos_bf,  qp,           sQt, 0,   (long)Lt * 128, 1536, 384, 128, 384, 8, 3, 148, 0 }; // 8
    gemm_grouped<6><<<dim3(156, 4), 256, 0, stream>>>(sc);

    // ---- 5: fused softmax (2048 html rows + 4096 text rows) ----
    softmax_fused<<<6144, 256, 0, stream>>>(scoresH, probsH, scoresT, probsT,
                                            qe, qp, H2Hmask, H2Tmask, T2Tmask,
                                            scale);

    // ---- 6: grouped PV GEMMs at 64^2 (K=1536 stacked V; 576 blocks = 2.25/CU) ----
    Segs pv;
    pv.s[0] = { probsH, VTs, out + (long)Lt * 384, sQh, sV, sOut, 1536, 1536, 384, 1536,  8, 3,  0, 0 }; // 48
    pv.s[1] = { probsT, VTs, out,                  sQt, sV, sOut, 1536, 1536, 384, 1536, 16, 4, 48, 0 }; // 96
    pv.s[2] = pv.s[1]; pv.s[3] = pv.s[1]; pv.s[4] = pv.s[1]; pv.s[5] = pv.s[1];
    gemm_grouped64<2><<<dim3(144, 4), 256, 0, stream>>>(pv);
}